// Round 1
// baseline (934.864 us; speedup 1.0000x reference)
//
#include <hip/hip_runtime.h>

// Problem constants
#define BATCH   16
#define CIN     256
#define EDIM    256
#define HW      4096            // 64*64
#define NPIX    65536           // BATCH*HW
#define RREAL   365
#define RPAD    368             // 23 chunks of 16
#define NCHUNK  23
#define OUTPLANE 23920640       // B*R*HW

typedef __attribute__((ext_vector_type(8))) short short8;
typedef __attribute__((ext_vector_type(4))) float f32x4;

__device__ __forceinline__ unsigned short f2bf(float f) {
    union { float f; unsigned u; } v; v.f = f;
    unsigned r = v.u + 0x7fffu + ((v.u >> 16) & 1u);   // RNE
    return (unsigned short)(r >> 16);
}

// ---------------- K0: conv_w fp32 -> bf16 ----------------
__global__ void k_cvt_w(const float* __restrict__ w, unsigned short* __restrict__ wbf) {
    int i = blockIdx.x * 256 + threadIdx.x;
    wbf[i] = f2bf(w[i]);
}

// ---------------- K1: reps -> 3 bf16 planes [RPAD][256] ----------------
__global__ __launch_bounds__(256) void k_reps(const float* __restrict__ reps,
                                              const float* __restrict__ negw,
                                              const float* __restrict__ negb,
                                              unsigned short* __restrict__ rp,
                                              unsigned short* __restrict__ rn0,
                                              unsigned short* __restrict__ rn1) {
    int r = blockIdx.x;
    int t = threadIdx.x;
    if (r >= RREAL) {           // zero-pad rows 365..367
        rp[r*256 + t] = 0; rn0[r*256 + t] = 0; rn1[r*256 + t] = 0;
        return;
    }
    __shared__ __align__(16) float sa[256];   // |reps|
    __shared__ float red[8];
    float rv = reps[r*256 + t];
    float av = fabsf(rv);
    sa[t] = av;
    __syncthreads();
    const float4* a4 = (const float4*)sa;
    const float4* w0 = (const float4*)(negw + (size_t)t * 256);
    const float4* w1 = (const float4*)(negw + (size_t)(256 + t) * 256);
    float acc0 = negb[t], acc1 = negb[256 + t];
    #pragma unroll 8
    for (int k = 0; k < 64; k++) {
        float4 a = a4[k];
        float4 x0 = w0[k], x1 = w1[k];
        acc0 += a.x*x0.x + a.y*x0.y + a.z*x0.z + a.w*x0.w;
        acc1 += a.x*x1.x + a.y*x1.y + a.z*x1.z + a.w*x1.w;
    }
    float sgn = (rv > 0.f) ? 1.f : ((rv < 0.f) ? -1.f : 0.f);
    float v0 = (acc0 + av) * sgn;
    float v1 = (acc1 + av) * sgn;
    float s0 = v0*v0, s1 = v1*v1;
    #pragma unroll
    for (int off = 32; off; off >>= 1) { s0 += __shfl_xor(s0, off); s1 += __shfl_xor(s1, off); }
    int wid = t >> 6;
    if ((t & 63) == 0) { red[wid] = s0; red[4 + wid] = s1; }
    __syncthreads();
    float t0 = red[0] + red[1] + red[2] + red[3];
    float t1 = red[4] + red[5] + red[6] + red[7];
    float i0 = 1.f / fmaxf(sqrtf(t0), 1e-12f);
    float i1 = 1.f / fmaxf(sqrtf(t1), 1e-12f);
    rp [r*256 + t] = f2bf(rv);
    rn0[r*256 + t] = f2bf(v0 * i0);
    rn1[r*256 + t] = f2bf(v1 * i1);
}

// ---------------- K2: conv1x1 + L2-norm -> emb bf16 [NPIX][256] ----------------
// MFMA: A = x tile (M=16 px), B = conv_w^T (N=16 e). Wave = 16 pixels, block = 64.
__global__ __launch_bounds__(256) void k_conv(const float* __restrict__ x,
                                              const unsigned short* __restrict__ wbf,
                                              const float* __restrict__ convb,
                                              unsigned short* __restrict__ emb) {
    int wave = threadIdx.x >> 6, lane = threadIdx.x & 63;
    int l15 = lane & 15, quad = lane >> 4;
    int px0 = blockIdx.x * 64 + wave * 16;
    int b = px0 >> 12, hw0 = px0 & 4095;
    const float* xb = x + (size_t)b * CIN * HW;
    int hwa = hw0 + l15;

    f32x4 acc[16];
    #pragma unroll
    for (int et = 0; et < 16; et++) acc[et] = (f32x4){0.f, 0.f, 0.f, 0.f};

    for (int k0 = 0; k0 < 8; k0++) {
        int c0 = k0 * 32 + quad * 8;
        short8 af;
        #pragma unroll
        for (int j = 0; j < 8; j++) {
            float xv = xb[(size_t)(c0 + j) * HW + hwa];
            ((unsigned short*)&af)[j] = f2bf(xv);
        }
        #pragma unroll
        for (int et = 0; et < 16; et++) {
            short8 bf = *(const short8*)(wbf + (size_t)(et*16 + l15) * 256 + k0*32 + quad*8);
            acc[et] = __builtin_amdgcn_mfma_f32_16x16x32_bf16(af, bf, acc[et], 0, 0, 0);
        }
    }
    // epilogue: + bias, L2-normalize over e (256), store bf16
    #pragma unroll
    for (int reg = 0; reg < 4; reg++) {
        int px = px0 + quad * 4 + reg;
        float v[16];
        float s = 0.f;
        #pragma unroll
        for (int et = 0; et < 16; et++) {
            float vv = acc[et][reg] + convb[et*16 + l15];
            v[et] = vv; s += vv * vv;
        }
        s += __shfl_xor(s, 1); s += __shfl_xor(s, 2);
        s += __shfl_xor(s, 4); s += __shfl_xor(s, 8);
        float inv = 1.f / fmaxf(sqrtf(s), 1e-12f);
        #pragma unroll
        for (int et = 0; et < 16; et++)
            emb[(size_t)px * 256 + et*16 + l15] = f2bf(v[et] * inv);
    }
}

// ---------------- K3: distances + probs + everything ----------------
// MFMA: A = reps chunk (M=16 r), B = emb (N=16 px, frags held in VGPRs all kernel).
__global__ __launch_bounds__(256) void k_main(const unsigned short* __restrict__ emb,
                                              const unsigned short* __restrict__ rp,
                                              const unsigned short* __restrict__ rn0,
                                              const unsigned short* __restrict__ rn1,
                                              float* __restrict__ oCls,
                                              float* __restrict__ oClsNeg,
                                              float* __restrict__ oDist,
                                              float* __restrict__ oDneg,
                                              float* __restrict__ oPori,
                                              float* __restrict__ sumij) {
    int wave = threadIdx.x >> 6, lane = threadIdx.x & 63;
    int l15 = lane & 15, quad = lane >> 4;
    int px0 = blockIdx.x * 64 + wave * 16;
    int b = px0 >> 12, hw0 = px0 & 4095;
    int hw = hw0 + l15;
    size_t obase = (size_t)b * RREAL * HW;

    short8 ef[8];
    #pragma unroll
    for (int k0 = 0; k0 < 8; k0++)
        ef[k0] = *(const short8*)(emb + (size_t)(px0 + l15) * 256 + k0*32 + quad*8);

    float sumP = 0.f;
    for (int ch = 0; ch < NCHUNK; ch++) {
        int r0 = ch * 16;
        f32x4 aP  = (f32x4){0.f,0.f,0.f,0.f};
        f32x4 aN0 = (f32x4){0.f,0.f,0.f,0.f};
        f32x4 aN1 = (f32x4){0.f,0.f,0.f,0.f};
        size_t rrow = (size_t)(r0 + l15) * 256 + quad * 8;
        #pragma unroll
        for (int k0 = 0; k0 < 8; k0++) {
            short8 fp = *(const short8*)(rp  + rrow + k0*32);
            short8 f0 = *(const short8*)(rn0 + rrow + k0*32);
            short8 f1 = *(const short8*)(rn1 + rrow + k0*32);
            aP  = __builtin_amdgcn_mfma_f32_16x16x32_bf16(fp, ef[k0], aP , 0, 0, 0);
            aN0 = __builtin_amdgcn_mfma_f32_16x16x32_bf16(f0, ef[k0], aN0, 0, 0, 0);
            aN1 = __builtin_amdgcn_mfma_f32_16x16x32_bf16(f1, ef[k0], aN1, 0, 0, 0);
        }
        #pragma unroll
        for (int reg = 0; reg < 4; reg++) {
            int r = r0 + quad * 4 + reg;
            float d2 = fmaxf(2.f - 2.f * aP[reg], 0.f);
            float e0 = fmaxf(2.f - 2.f * aN0[reg], 0.f);
            float e1 = fmaxf(2.f - 2.f * aN1[reg], 0.f);
            float d   = sqrtf(d2);
            float dn0 = sqrtf(e0);
            float dn1 = sqrtf(e1);
            float pori = __expf(-2.f * d2);
            float pn0  = __expf(-2.f * e0);
            float pn1  = __expf(-2.f * e1);
            float clsneg = fmaxf(pn0, pn1);
            float dnmin  = fminf(dn0, dn1);
            float tt = fmaf(-0.3f, dnmin, d + 0.6f);   // d + 0.3*(2 - dnmin)
            float probs = __expf(-2.f * tt * tt);
            if (r < RREAL) {
                size_t idx = obase + ((size_t)r << 12) + hw;
                oDist[idx]   = d;
                oPori[idx]   = pori;
                oClsNeg[idx] = clsneg;
                oCls[idx]    = probs;          // numerator; divided in k_div
                size_t idn = obase * 2 + ((size_t)(r * 2) << 12) + hw;
                oDneg[idn]        = dn0;
                oDneg[idn + HW]   = dn1;
                sumP += probs;
            }
        }
    }
    sumP += __shfl_xor(sumP, 16);
    sumP += __shfl_xor(sumP, 32);
    if (lane < 16) sumij[px0 + lane] = sumP;   // each wave owns its 16 pixels
}

// ---------------- K4: cls_score normalization ----------------
__global__ void k_div(float* __restrict__ oCls, const float* __restrict__ sumij) {
    size_t base = ((size_t)blockIdx.x * 256 + threadIdx.x) * 4;
    float4 p = *(float4*)(oCls + base);
    int b  = (int)(base / ((size_t)RREAL * HW));
    int hw = (int)(base & 4095);
    float4 s = *(const float4*)(sumij + b * HW + hw);
    p.x /= s.x; p.y /= s.y; p.z /= s.z; p.w /= s.w;
    *(float4*)(oCls + base) = p;
}

extern "C" void kernel_launch(void* const* d_in, const int* in_sizes, int n_in,
                              void* d_out, int out_size, void* d_ws, size_t ws_size,
                              hipStream_t stream) {
    const float* x      = (const float*)d_in[0];
    const float* conv_w = (const float*)d_in[1];
    const float* conv_b = (const float*)d_in[2];
    const float* reps   = (const float*)d_in[3];
    const float* neg_w  = (const float*)d_in[4];
    const float* neg_b  = (const float*)d_in[5];
    float* out = (float*)d_out;

    // workspace layout (needs ~33 MB)
    char* ws = (char*)d_ws;
    unsigned short* emb = (unsigned short*)ws;                       // NPIX*256*2 = 33,554,432
    unsigned short* rp  = (unsigned short*)(ws + 33554432);          // RPAD*256*2 each
    unsigned short* rn0 = rp  + RPAD * 256;
    unsigned short* rn1 = rn0 + RPAD * 256;
    unsigned short* wbf = rn1 + RPAD * 256;                          // 65536*2
    float* sumij = (float*)(ws + 33554432 + 3 * RPAD * 256 * 2 + 65536 * 2);

    float* oCls    = out;
    float* oClsNeg = out + (size_t)OUTPLANE;
    float* oDist   = out + (size_t)OUTPLANE * 2;
    float* oDneg   = out + (size_t)OUTPLANE * 3;
    float* oPori   = out + (size_t)OUTPLANE * 5;

    k_cvt_w<<<256, 256, 0, stream>>>(conv_w, wbf);
    k_reps <<<RPAD, 256, 0, stream>>>(reps, neg_w, neg_b, rp, rn0, rn1);
    k_conv <<<NPIX / 64, 256, 0, stream>>>(x, wbf, conv_b, emb);
    k_main <<<NPIX / 64, 256, 0, stream>>>(emb, rp, rn0, rn1,
                                           oCls, oClsNeg, oDist, oDneg, oPori, sumij);
    k_div  <<<OUTPLANE / 1024, 256, 0, stream>>>(oCls, sumij);
}